// Round 9
// baseline (599.995 us; speedup 1.0000x reference)
//
#include <hip/hip_runtime.h>
#include <math.h>

// ---------------------------------------------------------------------------
// Faster-RCNN head pipeline on gfx950.
// fp64 for everything selection-affecting (matches numpy f64 ordering).
//
// R1: NMS -> iou bit-matrix + 1-wave serial resolve.
// R2: f64 MFMA conv FAILED (f64 C/D layout != bf16 family).
// R3: probe-calibrated D scatter. PASS 893.
// R4: conv retile 2 blocks/CU -> 278us. PASS 847.
// R5: exact-round grid regressed conv (atomics x2); nms tweaks neutral.
// R6: fused cooperative kernel FAILED (coop launch never ran).
// R7: split dispatches + rebuilt NMS (speculative crit-word prefetch,
//     parallel far-propagate) + parallel rank. PASS 552. conv=278 (50%).
// R8: conv patch staged in FP32 (cvt to f64 at A-register load): LDS
//     44.5->23.5 KB, pad 35 (banks), launch_bounds(512,8) caps VGPR<=64
//     -> 4 blocks/CU. Staging overlaps MFMA across blocks.
// ---------------------------------------------------------------------------

#define H 40
#define W 40
#define CIN 2048
#define CMID 256
#define NBOX 8000   // 40*40*5
#define NCH 125     // NBOX / 64 chunks
#define ROWW 128    // padded row width (ullong words) of suppression matrix
#define MAXDET 300

typedef double d4 __attribute__((ext_vector_type(4)));

// ---------------------------------------------------------------------------
// Kernel 1: 3x3 SAME conv (2048 -> 256) via v_mfma_f64_16x16x4.
// Grid 1280 = 20 M-tiles x 2 N-halves x 32 K-splits (64 ch via 2 LDS slabs).
// Block 512 = 8 waves; wave owns 16 outch -> acc = 5 x d4 (40 VGPR).
// Patch staged as FP32 (23.5 KB), cvt to f64 at register load -> 4 blocks/CU.
// D mapping discovered at runtime via probe MFMAs.
// ---------------------------------------------------------------------------
__global__ __launch_bounds__(512, 8) void conv3x3_kernel(
    const float* __restrict__ feat, const float* __restrict__ conv_w,
    double* __restrict__ xsum) {
  // fp32 patch; inner pad 35 -> A-read bank aliasing <= 2-way (free).
  __shared__ float patch[4][42][35];
  const int t = threadIdx.x;
  const int blk = blockIdx.x;
  const int sk = blk & 31;          // K-split: channels c0..c0+63
  const int nh = (blk >> 5) & 1;    // N-half: outch nh*128..+128
  const int mt = blk >> 6;          // M-tile: rows y0, y0+1
  const int y0 = mt * 2;
  const int c0 = sk * 64;

  const int wave = t >> 6, lane = t & 63;
  const int nl = lane & 15;   // A: m-index, B: n-index
  const int kk = lane >> 4;   // k-index within K=4 step
  const int n1 = nh * 128 + wave * 16;

  // --- D-layout self-calibration probes (cost: 2 MFMAs) -------------------
  d4 zero = (d4)0.0;
  double pa1 = (kk == 0) ? 1.0 : 0.0;
  double pb1 = (kk == 0) ? (double)nl : 0.0;
  d4 dcol = __builtin_amdgcn_mfma_f64_16x16x4f64(pa1, pb1, zero, 0, 0, 0);
  double pa2 = (kk == 0) ? (double)nl : 0.0;
  double pb2 = (kk == 0) ? 1.0 : 0.0;
  d4 drow = __builtin_amdgcn_mfma_f64_16x16x4f64(pa2, pb2, zero, 0, 0, 0);

  int apy[5], apx[5];
#pragma unroll
  for (int f = 0; f < 5; ++f) {
    int pos = f * 16 + nl;
    apy[f] = pos / 40;
    apx[f] = pos % 40;
  }

  d4 acc[5];
#pragma unroll
  for (int f = 0; f < 5; ++f) acc[f] = (d4)0.0;

  for (int s2 = 0; s2 < 2; ++s2) {
    const int ch = c0 + s2 * 32;
    if (s2) __syncthreads();  // previous slab fully consumed
    for (int i = t; i < 4 * 42 * 32; i += 512) {
      int c = i & 31;
      int rc = i >> 5;
      int col = rc % 42;
      int row = rc / 42;
      int gy = y0 - 1 + row;
      int gx = col - 1;
      float v = 0.f;
      if (gy >= 0 && gy < H && gx >= 0 && gx < W)
        v = feat[(gy * W + gx) * CIN + ch + c];
      patch[row][col][c] = v;
    }
    __syncthreads();

    for (int tap = 0; tap < 9; ++tap) {
      const int dy = tap / 3, dx = tap % 3;
      const float* ap0 = &patch[apy[0] + dy][apx[0] + dx][kk];
      const float* ap1 = &patch[apy[1] + dy][apx[1] + dx][kk];
      const float* ap2 = &patch[apy[2] + dy][apx[2] + dx][kk];
      const float* ap3 = &patch[apy[3] + dy][apx[3] + dx][kk];
      const float* ap4 = &patch[apy[4] + dy][apx[4] + dx][kk];
      const float* bp = conv_w + ((tap * CIN + ch + kk) * CMID + n1 + nl);
#pragma unroll
      for (int cq = 0; cq < 8; ++cq) {
        const int co = cq * 4;  // channel group offset (K=4 step)
        double b0 = (double)bp[co * CMID];
        double a0 = (double)ap0[co];
        double a1 = (double)ap1[co];
        double a2 = (double)ap2[co];
        double a3 = (double)ap3[co];
        double a4 = (double)ap4[co];
        acc[0] = __builtin_amdgcn_mfma_f64_16x16x4f64(a0, b0, acc[0], 0, 0, 0);
        acc[1] = __builtin_amdgcn_mfma_f64_16x16x4f64(a1, b0, acc[1], 0, 0, 0);
        acc[2] = __builtin_amdgcn_mfma_f64_16x16x4f64(a2, b0, acc[2], 0, 0, 0);
        acc[3] = __builtin_amdgcn_mfma_f64_16x16x4f64(a3, b0, acc[3], 0, 0, 0);
        acc[4] = __builtin_amdgcn_mfma_f64_16x16x4f64(a4, b0, acc[4], 0, 0, 0);
      }
    }
  }

  // Scatter via PROBED D mapping; combine K-splits with fp64 atomicAdd.
#pragma unroll
  for (int f = 0; f < 5; ++f)
#pragma unroll
    for (int i = 0; i < 4; ++i) {
      int pm = (int)drow[i];
      int pn = (int)dcol[i];
      int pos = f * 16 + pm;
      int py = pos / 40, px = pos % 40;
      int gpos = (y0 + py) * W + px;
      atomicAdd(&xsum[gpos * CMID + n1 + pn], acc[f][i]);
    }
}

// ---------------------------------------------------------------------------
// Kernel 2: bias+ReLU, cls/reg 1x1 convs in fp64, sigmoid score, box decode.
// ---------------------------------------------------------------------------
__global__ __launch_bounds__(256) void heads_kernel(
    const double* __restrict__ xsum, const float* __restrict__ conv_b,
    const float* __restrict__ cls_w, const float* __restrict__ cls_b,
    const float* __restrict__ reg_w, const float* __restrict__ reg_b,
    double* __restrict__ scores, double* __restrict__ boxes) {
  __shared__ double xd[256];
  __shared__ double outv[32];
  const int p = blockIdx.x;
  const int t = threadIdx.x;
  double v = xsum[p * 256 + t] + (double)conv_b[t];
  xd[t] = v > 0.0 ? v : 0.0;
  __syncthreads();

  const int wave = t >> 6, lane = t & 63;
  for (int q = 0; q < 8; ++q) {
    int o = wave * 8 + q;
    if (o < 30) {  // uniform within wave
      double acc = 0.0;
      if (o < 10) {
#pragma unroll
        for (int k = 0; k < 4; ++k)
          acc += xd[lane * 4 + k] * (double)cls_w[(lane * 4 + k) * 10 + o];
      } else {
        int oo = o - 10;
#pragma unroll
        for (int k = 0; k < 4; ++k)
          acc += xd[lane * 4 + k] * (double)reg_w[(lane * 4 + k) * 20 + oo];
      }
#pragma unroll
      for (int off = 32; off > 0; off >>= 1) acc += __shfl_down(acc, off);
      if (lane == 0) outv[o] = acc;
    }
  }
  __syncthreads();

  if (t < 5) {
    const int a = t;
    double l0 = outv[2 * a] + (double)cls_b[2 * a];
    double l1 = outv[2 * a + 1] + (double)cls_b[2 * a + 1];
    double sc = 1.0 / (1.0 + exp(l0 - l1));  // == softmax[...,1]
    const int n = p * 5 + a;
    scores[n] = sc;
    double d0 = outv[10 + 4 * a + 0] + (double)reg_b[4 * a + 0];
    double d1 = outv[10 + 4 * a + 1] + (double)reg_b[4 * a + 1];
    double d2 = outv[10 + 4 * a + 2] + (double)reg_b[4 * a + 2];
    double d3 = outv[10 + 4 * a + 3] + (double)reg_b[4 * a + 3];
    double scale = (double)(32 << a);  // 32,64,128,256,512 (ratio=1)
    double wdt = exp(d2) * scale;
    double hgt = exp(d3) * scale;
    double xc = (double)(p % W) + d0;  // FEATURE_STRIDE = 1
    double yc = (double)(p / W) + d1;
    boxes[n * 4 + 0] = xc - 0.5 * wdt;
    boxes[n * 4 + 1] = yc - 0.5 * hgt;
    boxes[n * 4 + 2] = xc + 0.5 * wdt;
    boxes[n * 4 + 3] = yc + 0.5 * hgt;
  }
}

// ---------------------------------------------------------------------------
// Kernel 3: exact stable descending rank, fully parallel: 32 slices of 250 j
// per box i, shfl-reduce over the 32-subgroup. Grid 1000 x 256.
// ---------------------------------------------------------------------------
__global__ __launch_bounds__(256) void rank_kernel(
    const double* __restrict__ scores, const double* __restrict__ boxes,
    double* __restrict__ bs, double* __restrict__ area) {
  const int gid = blockIdx.x * 256 + threadIdx.x;
  const int i = gid >> 5;
  const int js = gid & 31;
  if (i >= NBOX) return;
  const double si = scores[i];
  int cnt = 0;
  const int j0 = js * 250;
#pragma unroll 5
  for (int j = j0; j < j0 + 250; ++j) {
    double sj = scores[j];
    cnt += (sj > si || (sj == si && j < i)) ? 1 : 0;
  }
#pragma unroll
  for (int off = 16; off > 0; off >>= 1) cnt += __shfl_down(cnt, off, 32);
  if (js == 0) {
    double b0 = boxes[i * 4 + 0], b1 = boxes[i * 4 + 1];
    double b2 = boxes[i * 4 + 2], b3 = boxes[i * 4 + 3];
    bs[cnt * 4 + 0] = b0;
    bs[cnt * 4 + 1] = b1;
    bs[cnt * 4 + 2] = b2;
    bs[cnt * 4 + 3] = b3;
    area[cnt] = (b2 - b0) * (b3 - b1);
  }
}

// ---------------------------------------------------------------------------
// Kernel 4a: suppression bit-matrix (upper-tri tiles only). Div-free:
// inter >= 0.7*union (identical decision; union > 0 always).
// ---------------------------------------------------------------------------
__global__ __launch_bounds__(256) void iou_matrix_kernel(
    const double* __restrict__ bs, const double* __restrict__ area,
    unsigned long long* __restrict__ supmat) {
  __shared__ double jx1[64], jy1[64], jx2[64], jy2[64], ja[64];
  __shared__ double ix1[64], iy1[64], ix2[64], iy2[64], ia[64];
  const int ti = blockIdx.x / NCH, tj = blockIdx.x % NCH;
  if (tj < ti) return;  // lower triangle never read
  const int t = threadIdx.x, wv = t >> 6, lane = t & 63;
  if (t < 64) {
    int j = tj * 64 + t;
    jx1[t] = bs[j * 4 + 0];
    jy1[t] = bs[j * 4 + 1];
    jx2[t] = bs[j * 4 + 2];
    jy2[t] = bs[j * 4 + 3];
    ja[t] = area[j];
  } else if (t < 128) {
    int l = t - 64;
    int i = ti * 64 + l;
    ix1[l] = bs[i * 4 + 0];
    iy1[l] = bs[i * 4 + 1];
    ix2[l] = bs[i * 4 + 2];
    iy2[l] = bs[i * 4 + 3];
    ia[l] = area[i];
  }
  __syncthreads();
  const double x1 = jx1[lane], y1 = jy1[lane], x2 = jx2[lane], y2 = jy2[lane];
  const double aj = ja[lane];
  const int jglob = tj * 64 + lane;
#pragma unroll 4
  for (int s = 0; s < 16; ++s) {
    const int il = wv * 16 + s;
    const int i = ti * 64 + il;
    const double bx1 = ix1[il], by1 = iy1[il], bx2 = ix2[il], by2 = iy2[il];
    const double ai = ia[il];
    double iw = fmin(x2, bx2) - fmax(x1, bx1);
    iw = iw > 0.0 ? iw : 0.0;
    double ih = fmin(y2, by2) - fmax(y1, by1);
    ih = ih > 0.0 ? ih : 0.0;
    double inter = iw * ih;
    bool sup = (jglob > i) && (inter >= 0.7 * (ai + aj - inter));
    unsigned long long wmask = __ballot(sup ? 1 : 0);
    if (lane == 0) supmat[(size_t)i * ROWW + tj] = wmask;
  }
}

// ---------------------------------------------------------------------------
// Kernel 4b: greedy resolution, 1024 threads, 1 barrier/chunk.
// Wave0: resolve chunk tc using mask[tc] | crit (crit computed last iter
// from the speculatively prefetched column). Waves 1-7: propagate chunk
// tc-1's kept rows into mask words >= tc+1 (parallel over rows x words).
// ---------------------------------------------------------------------------
__global__ __launch_bounds__(1024) void nms_serial_kernel(
    const double* __restrict__ bs,
    const unsigned long long* __restrict__ supmat,
    float* __restrict__ rois_out) {
  __shared__ unsigned long long mask[NCH];
  __shared__ int selK[MAXDET];
  __shared__ int kbl[2][64];
  __shared__ int kcnt_sh[2];
  __shared__ int nk_sh;
  const int t = threadIdx.x, lane = t & 63;

  for (int q = t; q < NCH; q += 1024) mask[q] = 0ull;
  if (t == 0) {
    kcnt_sh[0] = kcnt_sh[1] = 0;
    nk_sh = 0;
  }
  __syncthreads();

  unsigned long long wdiag = 0ull, wcrit = 0ull, crit = 0ull;
  if (t < 64) {
    wdiag = supmat[(size_t)lane * ROWW + 0];
    wcrit = supmat[(size_t)lane * ROWW + 1];  // NCH > 1
  }
  int nk = 0;
  for (int tc = 0; tc < NCH; ++tc) {
    const int par = tc & 1;
    if (t < 64) {
      unsigned long long m = mask[tc] | crit;
      unsigned long long cand = ~m;
      unsigned long long keptbits = 0ull;
      int cnt = 0;
      while (cand && nk < MAXDET) {  // uniform serial loop
        int b = __ffsll(cand) - 1;
        unsigned long long bit = 1ull << b;
        keptbits |= bit;
        if (lane == 0) {
          selK[nk] = tc * 64 + b;
          kbl[par][cnt] = b;
        }
        cnt++;
        nk++;
        unsigned long long row = __shfl(wdiag, b);
        cand &= ~(row | bit);
      }
      // crit for chunk tc+1: OR of prefetched column tc+1 over kept lanes.
      unsigned long long v = ((keptbits >> lane) & 1ull) ? wcrit : 0ull;
#pragma unroll
      for (int off = 32; off > 0; off >>= 1) v |= __shfl_xor(v, off);
      crit = v;
      // prefetch chunk tc+1's diag and crit columns (guard past NCH).
      if (tc + 1 < NCH) {
        wdiag = supmat[(size_t)((tc + 1) * 64 + lane) * ROWW + (tc + 1)];
        wcrit = (tc + 2 < NCH)
                    ? supmat[(size_t)((tc + 1) * 64 + lane) * ROWW + (tc + 2)]
                    : 0ull;
      }
      if (lane == 0) {
        kcnt_sh[par] = cnt;
        nk_sh = nk;
      }
    } else if (tc > 0) {
      // propagate chunk tc-1's kept rows into words >= tc+1.
      const int pp = par ^ 1;
      const int k = kcnt_sh[pp];
      const int ptc = tc - 1;
      const int w0 = ptc + 2;  // == tc+1
      const int nwords = NCH - w0;
      if (k > 0 && nwords > 0) {
        const int npairs = k * nwords;
        for (int q = t - 64; q < npairs; q += 1024 - 64) {
          int b = kbl[pp][q / nwords];
          int w = w0 + q % nwords;
          unsigned long long r = supmat[(size_t)(ptc * 64 + b) * ROWW + w];
          if (r) {
            unsigned int* mw = (unsigned int*)&mask[w];
            unsigned int lo = (unsigned int)r;
            unsigned int hi = (unsigned int)(r >> 32);
            if (lo) atomicOr(&mw[0], lo);
            if (hi) atomicOr(&mw[1], hi);
          }
        }
      }
    }
    __syncthreads();
    nk = nk_sh;
    if (nk >= MAXDET) break;
  }
  __syncthreads();

  const int NK = nk < MAXDET ? nk : MAXDET;
  for (int r = t; r < MAXDET; r += 1024) {
    if (r < NK) {
      int p = selK[r];
      rois_out[r * 4 + 0] = (float)bs[p * 4 + 0];
      rois_out[r * 4 + 1] = (float)bs[p * 4 + 1];
      rois_out[r * 4 + 2] = (float)bs[p * 4 + 2];
      rois_out[r * 4 + 3] = (float)bs[p * 4 + 3];
    } else {  // rois = b[sel] * 0 exactly
      rois_out[r * 4 + 0] = 0.f;
      rois_out[r * 4 + 1] = 0.f;
      rois_out[r * 4 + 2] = 0.f;
      rois_out[r * 4 + 3] = 0.f;
    }
  }
}

// ---------------------------------------------------------------------------
// Kernel 5: FC head (fp32; tolerances generous, softmax saturated).
// ---------------------------------------------------------------------------
__global__ __launch_bounds__(256) void rcnn_head_kernel(
    const float* __restrict__ rois, const float* __restrict__ fc1_w,
    const float* __restrict__ fc1_b, const float* __restrict__ clsh_w,
    const float* __restrict__ clsh_b, const float* __restrict__ regh_w,
    const float* __restrict__ regh_b, float* __restrict__ out) {
  __shared__ float red[256 * 8];
  const int r = blockIdx.x, t = threadIdx.x;
  const float r0 = rois[r * 4 + 0], r1 = rois[r * 4 + 1];
  const float r2 = rois[r * 4 + 2], r3 = rois[r * 4 + 3];
  float pc[4] = {0, 0, 0, 0}, pb[4] = {0, 0, 0, 0};
#pragma unroll
  for (int q = 0; q < 4; ++q) {
    int j = t * 4 + q;
    float f = r0 * fc1_w[j] + r1 * fc1_w[1024 + j] + r2 * fc1_w[2048 + j] +
              r3 * fc1_w[3072 + j] + fc1_b[j];
    f = fmaxf(f, 0.f);
#pragma unroll
    for (int c = 0; c < 4; ++c) {
      pc[c] += f * clsh_w[j * 4 + c];
      pb[c] += f * regh_w[j * 4 + c];
    }
  }
#pragma unroll
  for (int u = 0; u < 4; ++u) {
    red[t * 8 + u] = pc[u];
    red[t * 8 + 4 + u] = pb[u];
  }
  __syncthreads();
  for (int s = 128; s > 0; s >>= 1) {
    if (t < s) {
#pragma unroll
      for (int u = 0; u < 8; ++u) red[t * 8 + u] += red[(t + s) * 8 + u];
    }
    __syncthreads();
  }
  if (t == 0) {
    float lg[4];
    float m = -1e30f;
#pragma unroll
    for (int c = 0; c < 4; ++c) {
      lg[c] = red[c] + clsh_b[c];
      m = fmaxf(m, lg[c]);
    }
    float s = 0.f;
#pragma unroll
    for (int c = 0; c < 4; ++c) {
      lg[c] = expf(lg[c] - m);
      s += lg[c];
    }
#pragma unroll
    for (int c = 0; c < 4; ++c) out[r * 4 + c] = lg[c] / s;
#pragma unroll
    for (int k = 0; k < 4; ++k)
      out[1200 + r * 4 + k] = red[4 + k] + regh_b[k];
  }
}

// ---------------------------------------------------------------------------
extern "C" void kernel_launch(void* const* d_in, const int* in_sizes, int n_in,
                              void* d_out, int out_size, void* d_ws,
                              size_t ws_size, hipStream_t stream) {
  const float* feat = (const float*)d_in[0];
  const float* conv_w = (const float*)d_in[1];
  const float* conv_b = (const float*)d_in[2];
  const float* cls_w = (const float*)d_in[3];
  const float* cls_b = (const float*)d_in[4];
  const float* reg_w = (const float*)d_in[5];
  const float* reg_b = (const float*)d_in[6];
  const float* fc1_w = (const float*)d_in[7];
  const float* fc1_b = (const float*)d_in[8];
  const float* clsh_w = (const float*)d_in[9];
  const float* clsh_b = (const float*)d_in[10];
  const float* regh_w = (const float*)d_in[11];
  const float* regh_b = (const float*)d_in[12];
  float* out = (float*)d_out;

  char* w = (char*)d_ws;
  double* xsum = (double*)(w);                 // 1600*256*8   = 3,276,800 B
  double* scores = (double*)(w + 3276800);     // 8000*8       =    64,000 B
  double* boxes = (double*)(w + 3340800);      // 8000*4*8     =   256,000 B
  double* bs = (double*)(w + 3596800);         // 8000*4*8     =   256,000 B
  double* area = (double*)(w + 3852800);       // 8000*8       =    64,000 B
  unsigned long long* supmat =
      (unsigned long long*)(w + 3916800);      // 8000*128*8   = 8,192,000 B

  hipMemsetAsync(xsum, 0, 3276800, stream);
  conv3x3_kernel<<<1280, 512, 0, stream>>>(feat, conv_w, xsum);
  heads_kernel<<<1600, 256, 0, stream>>>(xsum, conv_b, cls_w, cls_b, reg_w,
                                         reg_b, scores, boxes);
  rank_kernel<<<1000, 256, 0, stream>>>(scores, boxes, bs, area);
  iou_matrix_kernel<<<NCH * NCH, 256, 0, stream>>>(bs, area, supmat);
  nms_serial_kernel<<<1, 1024, 0, stream>>>(bs, supmat, out + 2400);
  rcnn_head_kernel<<<300, 256, 0, stream>>>(out + 2400, fc1_w, fc1_b, clsh_w,
                                            clsh_b, regh_w, regh_b, out);
}

// Round 10
// 574.755 us; speedup vs baseline: 1.0439x; 1.0439x over previous
//
#include <hip/hip_runtime.h>
#include <math.h>

// ---------------------------------------------------------------------------
// Faster-RCNN head pipeline on gfx950.
// fp64 for everything selection-affecting (matches numpy f64 ordering).
//
// R1: NMS -> iou bit-matrix + 1-wave serial resolve.
// R2: f64 MFMA conv FAILED (f64 C/D layout != bf16 family).
// R3: probe-calibrated D scatter. PASS 893.
// R4: conv retile 2 blocks/CU -> 278us. PASS 847.
// R5: exact-round grid regressed conv (atomics x2); nms tweaks neutral.
// R6: fused cooperative kernel FAILED (coop launch never ran).
// R7: split dispatches + rebuilt NMS + parallel rank. PASS 552. conv=278.
// R8: fp32 patch + launch_bounds(512,8) REGRESSED 318us: VGPR capped at 32
//     (< the ~60 live set incl. 40-reg acc) -> scratch spill (FETCH 37->89MB,
//     WRITE 102->224MB). Lesson: the 2nd launch_bounds arg is a hard VGPR cap.
// R9: fp32 staging kept; launch_bounds(512,6) -> VGPR cap 85, no spill;
//     occupancy self-selects 3-4 blocks/CU (LDS 23.5KB allows 6).
// ---------------------------------------------------------------------------

#define H 40
#define W 40
#define CIN 2048
#define CMID 256
#define NBOX 8000   // 40*40*5
#define NCH 125     // NBOX / 64 chunks
#define ROWW 128    // padded row width (ullong words) of suppression matrix
#define MAXDET 300

typedef double d4 __attribute__((ext_vector_type(4)));

// ---------------------------------------------------------------------------
// Kernel 1: 3x3 SAME conv (2048 -> 256) via v_mfma_f64_16x16x4.
// Grid 1280 = 20 M-tiles x 2 N-halves x 32 K-splits (64 ch via 2 LDS slabs).
// Block 512 = 8 waves; wave owns 16 outch -> acc = 5 x d4 (40 VGPR).
// Patch staged as FP32 (23.5 KB), cvt to f64 at register load.
// launch_bounds(512,6): VGPR cap 85 — enough for the ~60 live set (no
// spill), while LDS permits up to 6 blocks/CU; HW settles at 3-4 blocks.
// D mapping discovered at runtime via probe MFMAs.
// ---------------------------------------------------------------------------
__global__ __launch_bounds__(512, 6) void conv3x3_kernel(
    const float* __restrict__ feat, const float* __restrict__ conv_w,
    double* __restrict__ xsum) {
  // fp32 patch; inner pad 35 -> A-read bank aliasing <= 2-way (free).
  __shared__ float patch[4][42][35];
  const int t = threadIdx.x;
  const int blk = blockIdx.x;
  const int sk = blk & 31;          // K-split: channels c0..c0+63
  const int nh = (blk >> 5) & 1;    // N-half: outch nh*128..+128
  const int mt = blk >> 6;          // M-tile: rows y0, y0+1
  const int y0 = mt * 2;
  const int c0 = sk * 64;

  const int wave = t >> 6, lane = t & 63;
  const int nl = lane & 15;   // A: m-index, B: n-index
  const int kk = lane >> 4;   // k-index within K=4 step
  const int n1 = nh * 128 + wave * 16;

  // --- D-layout self-calibration probes (cost: 2 MFMAs) -------------------
  d4 zero = (d4)0.0;
  double pa1 = (kk == 0) ? 1.0 : 0.0;
  double pb1 = (kk == 0) ? (double)nl : 0.0;
  d4 dcol = __builtin_amdgcn_mfma_f64_16x16x4f64(pa1, pb1, zero, 0, 0, 0);
  double pa2 = (kk == 0) ? (double)nl : 0.0;
  double pb2 = (kk == 0) ? 1.0 : 0.0;
  d4 drow = __builtin_amdgcn_mfma_f64_16x16x4f64(pa2, pb2, zero, 0, 0, 0);

  int apy[5], apx[5];
#pragma unroll
  for (int f = 0; f < 5; ++f) {
    int pos = f * 16 + nl;
    apy[f] = pos / 40;
    apx[f] = pos % 40;
  }

  d4 acc[5];
#pragma unroll
  for (int f = 0; f < 5; ++f) acc[f] = (d4)0.0;

  for (int s2 = 0; s2 < 2; ++s2) {
    const int ch = c0 + s2 * 32;
    if (s2) __syncthreads();  // previous slab fully consumed
    for (int i = t; i < 4 * 42 * 32; i += 512) {
      int c = i & 31;
      int rc = i >> 5;
      int col = rc % 42;
      int row = rc / 42;
      int gy = y0 - 1 + row;
      int gx = col - 1;
      float v = 0.f;
      if (gy >= 0 && gy < H && gx >= 0 && gx < W)
        v = feat[(gy * W + gx) * CIN + ch + c];
      patch[row][col][c] = v;
    }
    __syncthreads();

    for (int tap = 0; tap < 9; ++tap) {
      const int dy = tap / 3, dx = tap % 3;
      const float* ap0 = &patch[apy[0] + dy][apx[0] + dx][kk];
      const float* ap1 = &patch[apy[1] + dy][apx[1] + dx][kk];
      const float* ap2 = &patch[apy[2] + dy][apx[2] + dx][kk];
      const float* ap3 = &patch[apy[3] + dy][apx[3] + dx][kk];
      const float* ap4 = &patch[apy[4] + dy][apx[4] + dx][kk];
      const float* bp = conv_w + ((tap * CIN + ch + kk) * CMID + n1 + nl);
#pragma unroll
      for (int cq = 0; cq < 8; ++cq) {
        const int co = cq * 4;  // channel group offset (K=4 step)
        double b0 = (double)bp[co * CMID];
        double a0 = (double)ap0[co];
        double a1 = (double)ap1[co];
        double a2 = (double)ap2[co];
        double a3 = (double)ap3[co];
        double a4 = (double)ap4[co];
        acc[0] = __builtin_amdgcn_mfma_f64_16x16x4f64(a0, b0, acc[0], 0, 0, 0);
        acc[1] = __builtin_amdgcn_mfma_f64_16x16x4f64(a1, b0, acc[1], 0, 0, 0);
        acc[2] = __builtin_amdgcn_mfma_f64_16x16x4f64(a2, b0, acc[2], 0, 0, 0);
        acc[3] = __builtin_amdgcn_mfma_f64_16x16x4f64(a3, b0, acc[3], 0, 0, 0);
        acc[4] = __builtin_amdgcn_mfma_f64_16x16x4f64(a4, b0, acc[4], 0, 0, 0);
      }
    }
  }

  // Scatter via PROBED D mapping; combine K-splits with fp64 atomicAdd.
#pragma unroll
  for (int f = 0; f < 5; ++f)
#pragma unroll
    for (int i = 0; i < 4; ++i) {
      int pm = (int)drow[i];
      int pn = (int)dcol[i];
      int pos = f * 16 + pm;
      int py = pos / 40, px = pos % 40;
      int gpos = (y0 + py) * W + px;
      atomicAdd(&xsum[gpos * CMID + n1 + pn], acc[f][i]);
    }
}

// ---------------------------------------------------------------------------
// Kernel 2: bias+ReLU, cls/reg 1x1 convs in fp64, sigmoid score, box decode.
// ---------------------------------------------------------------------------
__global__ __launch_bounds__(256) void heads_kernel(
    const double* __restrict__ xsum, const float* __restrict__ conv_b,
    const float* __restrict__ cls_w, const float* __restrict__ cls_b,
    const float* __restrict__ reg_w, const float* __restrict__ reg_b,
    double* __restrict__ scores, double* __restrict__ boxes) {
  __shared__ double xd[256];
  __shared__ double outv[32];
  const int p = blockIdx.x;
  const int t = threadIdx.x;
  double v = xsum[p * 256 + t] + (double)conv_b[t];
  xd[t] = v > 0.0 ? v : 0.0;
  __syncthreads();

  const int wave = t >> 6, lane = t & 63;
  for (int q = 0; q < 8; ++q) {
    int o = wave * 8 + q;
    if (o < 30) {  // uniform within wave
      double acc = 0.0;
      if (o < 10) {
#pragma unroll
        for (int k = 0; k < 4; ++k)
          acc += xd[lane * 4 + k] * (double)cls_w[(lane * 4 + k) * 10 + o];
      } else {
        int oo = o - 10;
#pragma unroll
        for (int k = 0; k < 4; ++k)
          acc += xd[lane * 4 + k] * (double)reg_w[(lane * 4 + k) * 20 + oo];
      }
#pragma unroll
      for (int off = 32; off > 0; off >>= 1) acc += __shfl_down(acc, off);
      if (lane == 0) outv[o] = acc;
    }
  }
  __syncthreads();

  if (t < 5) {
    const int a = t;
    double l0 = outv[2 * a] + (double)cls_b[2 * a];
    double l1 = outv[2 * a + 1] + (double)cls_b[2 * a + 1];
    double sc = 1.0 / (1.0 + exp(l0 - l1));  // == softmax[...,1]
    const int n = p * 5 + a;
    scores[n] = sc;
    double d0 = outv[10 + 4 * a + 0] + (double)reg_b[4 * a + 0];
    double d1 = outv[10 + 4 * a + 1] + (double)reg_b[4 * a + 1];
    double d2 = outv[10 + 4 * a + 2] + (double)reg_b[4 * a + 2];
    double d3 = outv[10 + 4 * a + 3] + (double)reg_b[4 * a + 3];
    double scale = (double)(32 << a);  // 32,64,128,256,512 (ratio=1)
    double wdt = exp(d2) * scale;
    double hgt = exp(d3) * scale;
    double xc = (double)(p % W) + d0;  // FEATURE_STRIDE = 1
    double yc = (double)(p / W) + d1;
    boxes[n * 4 + 0] = xc - 0.5 * wdt;
    boxes[n * 4 + 1] = yc - 0.5 * hgt;
    boxes[n * 4 + 2] = xc + 0.5 * wdt;
    boxes[n * 4 + 3] = yc + 0.5 * hgt;
  }
}

// ---------------------------------------------------------------------------
// Kernel 3: exact stable descending rank, fully parallel: 32 slices of 250 j
// per box i, shfl-reduce over the 32-subgroup. Grid 1000 x 256.
// ---------------------------------------------------------------------------
__global__ __launch_bounds__(256) void rank_kernel(
    const double* __restrict__ scores, const double* __restrict__ boxes,
    double* __restrict__ bs, double* __restrict__ area) {
  const int gid = blockIdx.x * 256 + threadIdx.x;
  const int i = gid >> 5;
  const int js = gid & 31;
  if (i >= NBOX) return;
  const double si = scores[i];
  int cnt = 0;
  const int j0 = js * 250;
#pragma unroll 5
  for (int j = j0; j < j0 + 250; ++j) {
    double sj = scores[j];
    cnt += (sj > si || (sj == si && j < i)) ? 1 : 0;
  }
#pragma unroll
  for (int off = 16; off > 0; off >>= 1) cnt += __shfl_down(cnt, off, 32);
  if (js == 0) {
    double b0 = boxes[i * 4 + 0], b1 = boxes[i * 4 + 1];
    double b2 = boxes[i * 4 + 2], b3 = boxes[i * 4 + 3];
    bs[cnt * 4 + 0] = b0;
    bs[cnt * 4 + 1] = b1;
    bs[cnt * 4 + 2] = b2;
    bs[cnt * 4 + 3] = b3;
    area[cnt] = (b2 - b0) * (b3 - b1);
  }
}

// ---------------------------------------------------------------------------
// Kernel 4a: suppression bit-matrix (upper-tri tiles only). Div-free:
// inter >= 0.7*union (identical decision; union > 0 always).
// ---------------------------------------------------------------------------
__global__ __launch_bounds__(256) void iou_matrix_kernel(
    const double* __restrict__ bs, const double* __restrict__ area,
    unsigned long long* __restrict__ supmat) {
  __shared__ double jx1[64], jy1[64], jx2[64], jy2[64], ja[64];
  __shared__ double ix1[64], iy1[64], ix2[64], iy2[64], ia[64];
  const int ti = blockIdx.x / NCH, tj = blockIdx.x % NCH;
  if (tj < ti) return;  // lower triangle never read
  const int t = threadIdx.x, wv = t >> 6, lane = t & 63;
  if (t < 64) {
    int j = tj * 64 + t;
    jx1[t] = bs[j * 4 + 0];
    jy1[t] = bs[j * 4 + 1];
    jx2[t] = bs[j * 4 + 2];
    jy2[t] = bs[j * 4 + 3];
    ja[t] = area[j];
  } else if (t < 128) {
    int l = t - 64;
    int i = ti * 64 + l;
    ix1[l] = bs[i * 4 + 0];
    iy1[l] = bs[i * 4 + 1];
    ix2[l] = bs[i * 4 + 2];
    iy2[l] = bs[i * 4 + 3];
    ia[l] = area[i];
  }
  __syncthreads();
  const double x1 = jx1[lane], y1 = jy1[lane], x2 = jx2[lane], y2 = jy2[lane];
  const double aj = ja[lane];
  const int jglob = tj * 64 + lane;
#pragma unroll 4
  for (int s = 0; s < 16; ++s) {
    const int il = wv * 16 + s;
    const int i = ti * 64 + il;
    const double bx1 = ix1[il], by1 = iy1[il], bx2 = ix2[il], by2 = iy2[il];
    const double ai = ia[il];
    double iw = fmin(x2, bx2) - fmax(x1, bx1);
    iw = iw > 0.0 ? iw : 0.0;
    double ih = fmin(y2, by2) - fmax(y1, by1);
    ih = ih > 0.0 ? ih : 0.0;
    double inter = iw * ih;
    bool sup = (jglob > i) && (inter >= 0.7 * (ai + aj - inter));
    unsigned long long wmask = __ballot(sup ? 1 : 0);
    if (lane == 0) supmat[(size_t)i * ROWW + tj] = wmask;
  }
}

// ---------------------------------------------------------------------------
// Kernel 4b: greedy resolution, 1024 threads, 1 barrier/chunk.
// Wave0: resolve chunk tc using mask[tc] | crit (crit computed last iter
// from the speculatively prefetched column). Waves 1-7: propagate chunk
// tc-1's kept rows into mask words >= tc+1 (parallel over rows x words).
// ---------------------------------------------------------------------------
__global__ __launch_bounds__(1024) void nms_serial_kernel(
    const double* __restrict__ bs,
    const unsigned long long* __restrict__ supmat,
    float* __restrict__ rois_out) {
  __shared__ unsigned long long mask[NCH];
  __shared__ int selK[MAXDET];
  __shared__ int kbl[2][64];
  __shared__ int kcnt_sh[2];
  __shared__ int nk_sh;
  const int t = threadIdx.x, lane = t & 63;

  for (int q = t; q < NCH; q += 1024) mask[q] = 0ull;
  if (t == 0) {
    kcnt_sh[0] = kcnt_sh[1] = 0;
    nk_sh = 0;
  }
  __syncthreads();

  unsigned long long wdiag = 0ull, wcrit = 0ull, crit = 0ull;
  if (t < 64) {
    wdiag = supmat[(size_t)lane * ROWW + 0];
    wcrit = supmat[(size_t)lane * ROWW + 1];  // NCH > 1
  }
  int nk = 0;
  for (int tc = 0; tc < NCH; ++tc) {
    const int par = tc & 1;
    if (t < 64) {
      unsigned long long m = mask[tc] | crit;
      unsigned long long cand = ~m;
      unsigned long long keptbits = 0ull;
      int cnt = 0;
      while (cand && nk < MAXDET) {  // uniform serial loop
        int b = __ffsll(cand) - 1;
        unsigned long long bit = 1ull << b;
        keptbits |= bit;
        if (lane == 0) {
          selK[nk] = tc * 64 + b;
          kbl[par][cnt] = b;
        }
        cnt++;
        nk++;
        unsigned long long row = __shfl(wdiag, b);
        cand &= ~(row | bit);
      }
      // crit for chunk tc+1: OR of prefetched column tc+1 over kept lanes.
      unsigned long long v = ((keptbits >> lane) & 1ull) ? wcrit : 0ull;
#pragma unroll
      for (int off = 32; off > 0; off >>= 1) v |= __shfl_xor(v, off);
      crit = v;
      // prefetch chunk tc+1's diag and crit columns (guard past NCH).
      if (tc + 1 < NCH) {
        wdiag = supmat[(size_t)((tc + 1) * 64 + lane) * ROWW + (tc + 1)];
        wcrit = (tc + 2 < NCH)
                    ? supmat[(size_t)((tc + 1) * 64 + lane) * ROWW + (tc + 2)]
                    : 0ull;
      }
      if (lane == 0) {
        kcnt_sh[par] = cnt;
        nk_sh = nk;
      }
    } else if (tc > 0) {
      // propagate chunk tc-1's kept rows into words >= tc+1.
      const int pp = par ^ 1;
      const int k = kcnt_sh[pp];
      const int ptc = tc - 1;
      const int w0 = ptc + 2;  // == tc+1
      const int nwords = NCH - w0;
      if (k > 0 && nwords > 0) {
        const int npairs = k * nwords;
        for (int q = t - 64; q < npairs; q += 1024 - 64) {
          int b = kbl[pp][q / nwords];
          int w = w0 + q % nwords;
          unsigned long long r = supmat[(size_t)(ptc * 64 + b) * ROWW + w];
          if (r) {
            unsigned int* mw = (unsigned int*)&mask[w];
            unsigned int lo = (unsigned int)r;
            unsigned int hi = (unsigned int)(r >> 32);
            if (lo) atomicOr(&mw[0], lo);
            if (hi) atomicOr(&mw[1], hi);
          }
        }
      }
    }
    __syncthreads();
    nk = nk_sh;
    if (nk >= MAXDET) break;
  }
  __syncthreads();

  const int NK = nk < MAXDET ? nk : MAXDET;
  for (int r = t; r < MAXDET; r += 1024) {
    if (r < NK) {
      int p = selK[r];
      rois_out[r * 4 + 0] = (float)bs[p * 4 + 0];
      rois_out[r * 4 + 1] = (float)bs[p * 4 + 1];
      rois_out[r * 4 + 2] = (float)bs[p * 4 + 2];
      rois_out[r * 4 + 3] = (float)bs[p * 4 + 3];
    } else {  // rois = b[sel] * 0 exactly
      rois_out[r * 4 + 0] = 0.f;
      rois_out[r * 4 + 1] = 0.f;
      rois_out[r * 4 + 2] = 0.f;
      rois_out[r * 4 + 3] = 0.f;
    }
  }
}

// ---------------------------------------------------------------------------
// Kernel 5: FC head (fp32; tolerances generous, softmax saturated).
// ---------------------------------------------------------------------------
__global__ __launch_bounds__(256) void rcnn_head_kernel(
    const float* __restrict__ rois, const float* __restrict__ fc1_w,
    const float* __restrict__ fc1_b, const float* __restrict__ clsh_w,
    const float* __restrict__ clsh_b, const float* __restrict__ regh_w,
    const float* __restrict__ regh_b, float* __restrict__ out) {
  __shared__ float red[256 * 8];
  const int r = blockIdx.x, t = threadIdx.x;
  const float r0 = rois[r * 4 + 0], r1 = rois[r * 4 + 1];
  const float r2 = rois[r * 4 + 2], r3 = rois[r * 4 + 3];
  float pc[4] = {0, 0, 0, 0}, pb[4] = {0, 0, 0, 0};
#pragma unroll
  for (int q = 0; q < 4; ++q) {
    int j = t * 4 + q;
    float f = r0 * fc1_w[j] + r1 * fc1_w[1024 + j] + r2 * fc1_w[2048 + j] +
              r3 * fc1_w[3072 + j] + fc1_b[j];
    f = fmaxf(f, 0.f);
#pragma unroll
    for (int c = 0; c < 4; ++c) {
      pc[c] += f * clsh_w[j * 4 + c];
      pb[c] += f * regh_w[j * 4 + c];
    }
  }
#pragma unroll
  for (int u = 0; u < 4; ++u) {
    red[t * 8 + u] = pc[u];
    red[t * 8 + 4 + u] = pb[u];
  }
  __syncthreads();
  for (int s = 128; s > 0; s >>= 1) {
    if (t < s) {
#pragma unroll
      for (int u = 0; u < 8; ++u) red[t * 8 + u] += red[(t + s) * 8 + u];
    }
    __syncthreads();
  }
  if (t == 0) {
    float lg[4];
    float m = -1e30f;
#pragma unroll
    for (int c = 0; c < 4; ++c) {
      lg[c] = red[c] + clsh_b[c];
      m = fmaxf(m, lg[c]);
    }
    float s = 0.f;
#pragma unroll
    for (int c = 0; c < 4; ++c) {
      lg[c] = expf(lg[c] - m);
      s += lg[c];
    }
#pragma unroll
    for (int c = 0; c < 4; ++c) out[r * 4 + c] = lg[c] / s;
#pragma unroll
    for (int k = 0; k < 4; ++k)
      out[1200 + r * 4 + k] = red[4 + k] + regh_b[k];
  }
}

// ---------------------------------------------------------------------------
extern "C" void kernel_launch(void* const* d_in, const int* in_sizes, int n_in,
                              void* d_out, int out_size, void* d_ws,
                              size_t ws_size, hipStream_t stream) {
  const float* feat = (const float*)d_in[0];
  const float* conv_w = (const float*)d_in[1];
  const float* conv_b = (const float*)d_in[2];
  const float* cls_w = (const float*)d_in[3];
  const float* cls_b = (const float*)d_in[4];
  const float* reg_w = (const float*)d_in[5];
  const float* reg_b = (const float*)d_in[6];
  const float* fc1_w = (const float*)d_in[7];
  const float* fc1_b = (const float*)d_in[8];
  const float* clsh_w = (const float*)d_in[9];
  const float* clsh_b = (const float*)d_in[10];
  const float* regh_w = (const float*)d_in[11];
  const float* regh_b = (const float*)d_in[12];
  float* out = (float*)d_out;

  char* w = (char*)d_ws;
  double* xsum = (double*)(w);                 // 1600*256*8   = 3,276,800 B
  double* scores = (double*)(w + 3276800);     // 8000*8       =    64,000 B
  double* boxes = (double*)(w + 3340800);      // 8000*4*8     =   256,000 B
  double* bs = (double*)(w + 3596800);         // 8000*4*8     =   256,000 B
  double* area = (double*)(w + 3852800);       // 8000*8       =    64,000 B
  unsigned long long* supmat =
      (unsigned long long*)(w + 3916800);      // 8000*128*8   = 8,192,000 B

  hipMemsetAsync(xsum, 0, 3276800, stream);
  conv3x3_kernel<<<1280, 512, 0, stream>>>(feat, conv_w, xsum);
  heads_kernel<<<1600, 256, 0, stream>>>(xsum, conv_b, cls_w, cls_b, reg_w,
                                         reg_b, scores, boxes);
  rank_kernel<<<1000, 256, 0, stream>>>(scores, boxes, bs, area);
  iou_matrix_kernel<<<NCH * NCH, 256, 0, stream>>>(bs, area, supmat);
  nms_serial_kernel<<<1, 1024, 0, stream>>>(bs, supmat, out + 2400);
  rcnn_head_kernel<<<300, 256, 0, stream>>>(out + 2400, fc1_w, fc1_b, clsh_w,
                                            clsh_b, regh_w, regh_b, out);
}

// Round 11
// 550.470 us; speedup vs baseline: 1.0900x; 1.0441x over previous
//
#include <hip/hip_runtime.h>
#include <math.h>

// ---------------------------------------------------------------------------
// Faster-RCNN head pipeline on gfx950.
// fp64 for everything selection-affecting (matches numpy f64 ordering).
//
// R1: NMS -> iou bit-matrix + 1-wave serial resolve.
// R2: f64 MFMA conv FAILED (f64 C/D layout != bf16 family).
// R3: probe-calibrated D scatter. PASS 893.
// R4: conv retile 2 blocks/CU -> 278us. PASS 847.
// R5: exact-round grid regressed conv (atomics x2); nms tweaks neutral.
// R6: fused cooperative kernel FAILED (coop launch never ran).
// R7: split dispatches + rebuilt NMS + parallel rank. PASS 552. conv=278.
// R8: fp32 patch + bounds(512,8): VGPR capped 32 -> spill. 318us. FAIL.
// R9: bounds(512,6): still spill (40 VGPR + 40 AGPR unified). 300us. FAIL.
//     LESSON: 40-AGPR acc makes <=64 total regs impossible -> 2 blocks/CU
//     is structural; R7 fp64-staging config is the conv operating point.
//     MFMA-busy 203us ~= v_mfma_f64 throughput floor (~37 TF measured).
// R10: conv = exact R7 revert + ws_size-guarded split-K via partial slices
//     (plain stores, no atomics/memset on critical path; heads sums 32
//     slices). iou launches only the 7875 upper-tri tiles.
// ---------------------------------------------------------------------------

#define H 40
#define W 40
#define CIN 2048
#define CMID 256
#define NBOX 8000   // 40*40*5
#define NCH 125     // NBOX / 64 chunks
#define NTRI (NCH * (NCH + 1) / 2)  // 7875 upper-tri tiles
#define ROWW 128    // padded row width (ullong words) of suppression matrix
#define MAXDET 300
#define PSLICE 409600  // 1600*256 doubles per K-split partial slice

typedef double d4 __attribute__((ext_vector_type(4)));

// ---------------------------------------------------------------------------
// Kernel 1: 3x3 SAME conv (2048 -> 256) via v_mfma_f64_16x16x4. (R4/R7 exact)
// Grid 1280 = 20 M-tiles x 2 N-halves x 32 K-splits (64 ch via 2 LDS slabs).
// Block 512 = 8 waves; wave owns 16 outch -> acc = 5 x d4 (40 AGPR).
// use_part: write per-K-split partial slice (plain stores) instead of
// atomicAdd into xsum (fallback when workspace is small).
// D mapping discovered at runtime via probe MFMAs (f64 != bf16 family).
// ---------------------------------------------------------------------------
__global__ __launch_bounds__(512, 4) void conv3x3_kernel(
    const float* __restrict__ feat, const float* __restrict__ conv_w,
    double* __restrict__ xsum, double* __restrict__ part, int use_part) {
  __shared__ double patch[4][42][33];  // rows y0-1..y0+2, cols -1..40, 32ch+pad
  const int t = threadIdx.x;
  const int blk = blockIdx.x;
  const int sk = blk & 31;          // K-split: channels c0..c0+63
  const int nh = (blk >> 5) & 1;    // N-half: outch nh*128..+128
  const int mt = blk >> 6;          // M-tile: rows y0, y0+1
  const int y0 = mt * 2;
  const int c0 = sk * 64;

  const int wave = t >> 6, lane = t & 63;
  const int nl = lane & 15;   // A: m-index, B: n-index
  const int kk = lane >> 4;   // k-index within K=4 step
  const int n1 = nh * 128 + wave * 16;

  // --- D-layout self-calibration probes (cost: 2 MFMAs) -------------------
  d4 zero = (d4)0.0;
  double pa1 = (kk == 0) ? 1.0 : 0.0;
  double pb1 = (kk == 0) ? (double)nl : 0.0;
  d4 dcol = __builtin_amdgcn_mfma_f64_16x16x4f64(pa1, pb1, zero, 0, 0, 0);
  double pa2 = (kk == 0) ? (double)nl : 0.0;
  double pb2 = (kk == 0) ? 1.0 : 0.0;
  d4 drow = __builtin_amdgcn_mfma_f64_16x16x4f64(pa2, pb2, zero, 0, 0, 0);

  int apy[5], apx[5];
#pragma unroll
  for (int f = 0; f < 5; ++f) {
    int pos = f * 16 + nl;
    apy[f] = pos / 40;
    apx[f] = pos % 40;
  }

  d4 acc[5];
#pragma unroll
  for (int f = 0; f < 5; ++f) acc[f] = (d4)0.0;

  for (int s2 = 0; s2 < 2; ++s2) {
    const int ch = c0 + s2 * 32;
    if (s2) __syncthreads();  // previous slab fully consumed
    for (int i = t; i < 4 * 42 * 32; i += 512) {
      int c = i & 31;
      int rc = i >> 5;
      int col = rc % 42;
      int row = rc / 42;
      int gy = y0 - 1 + row;
      int gx = col - 1;
      double v = 0.0;
      if (gy >= 0 && gy < H && gx >= 0 && gx < W)
        v = (double)feat[(gy * W + gx) * CIN + ch + c];
      patch[row][col][c] = v;
    }
    __syncthreads();

    for (int tap = 0; tap < 9; ++tap) {
      const int dy = tap / 3, dx = tap % 3;
      const double* ap0 = &patch[apy[0] + dy][apx[0] + dx][kk];
      const double* ap1 = &patch[apy[1] + dy][apx[1] + dx][kk];
      const double* ap2 = &patch[apy[2] + dy][apx[2] + dx][kk];
      const double* ap3 = &patch[apy[3] + dy][apx[3] + dx][kk];
      const double* ap4 = &patch[apy[4] + dy][apx[4] + dx][kk];
      const float* bp = conv_w + ((tap * CIN + ch + kk) * CMID + n1 + nl);
#pragma unroll
      for (int cq = 0; cq < 8; ++cq) {
        const int co = cq * 4;
        double b0 = (double)bp[co * CMID];
        double a0 = ap0[co];
        double a1 = ap1[co];
        double a2 = ap2[co];
        double a3 = ap3[co];
        double a4 = ap4[co];
        acc[0] = __builtin_amdgcn_mfma_f64_16x16x4f64(a0, b0, acc[0], 0, 0, 0);
        acc[1] = __builtin_amdgcn_mfma_f64_16x16x4f64(a1, b0, acc[1], 0, 0, 0);
        acc[2] = __builtin_amdgcn_mfma_f64_16x16x4f64(a2, b0, acc[2], 0, 0, 0);
        acc[3] = __builtin_amdgcn_mfma_f64_16x16x4f64(a3, b0, acc[3], 0, 0, 0);
        acc[4] = __builtin_amdgcn_mfma_f64_16x16x4f64(a4, b0, acc[4], 0, 0, 0);
      }
    }
  }

  // Scatter via PROBED D mapping. use_part: plain stores into this K-split's
  // slice (disjoint across blocks); else atomicAdd combine into xsum.
  if (use_part) {
    double* dst = part + (size_t)sk * PSLICE;
#pragma unroll
    for (int f = 0; f < 5; ++f)
#pragma unroll
      for (int i = 0; i < 4; ++i) {
        int pm = (int)drow[i];
        int pn = (int)dcol[i];
        int pos = f * 16 + pm;
        int py = pos / 40, px = pos % 40;
        int gpos = (y0 + py) * W + px;
        dst[gpos * CMID + n1 + pn] = acc[f][i];
      }
  } else {
#pragma unroll
    for (int f = 0; f < 5; ++f)
#pragma unroll
      for (int i = 0; i < 4; ++i) {
        int pm = (int)drow[i];
        int pn = (int)dcol[i];
        int pos = f * 16 + pm;
        int py = pos / 40, px = pos % 40;
        int gpos = (y0 + py) * W + px;
        atomicAdd(&xsum[gpos * CMID + n1 + pn], acc[f][i]);
      }
  }
}

// ---------------------------------------------------------------------------
// Kernel 2: bias+ReLU, cls/reg 1x1 convs in fp64, sigmoid score, box decode.
// use_part: sum the 32 K-split partial slices (coalesced) instead of xsum.
// ---------------------------------------------------------------------------
__global__ __launch_bounds__(256) void heads_kernel(
    const double* __restrict__ xsum, const double* __restrict__ part,
    int use_part, const float* __restrict__ conv_b,
    const float* __restrict__ cls_w, const float* __restrict__ cls_b,
    const float* __restrict__ reg_w, const float* __restrict__ reg_b,
    double* __restrict__ scores, double* __restrict__ boxes) {
  __shared__ double xd[256];
  __shared__ double outv[32];
  const int p = blockIdx.x;
  const int t = threadIdx.x;
  double v;
  if (use_part) {
    double s = 0.0;
    const double* pp = part + p * 256 + t;
#pragma unroll
    for (int sl = 0; sl < 32; ++sl) s += pp[(size_t)sl * PSLICE];
    v = s + (double)conv_b[t];
  } else {
    v = xsum[p * 256 + t] + (double)conv_b[t];
  }
  xd[t] = v > 0.0 ? v : 0.0;
  __syncthreads();

  const int wave = t >> 6, lane = t & 63;
  for (int q = 0; q < 8; ++q) {
    int o = wave * 8 + q;
    if (o < 30) {  // uniform within wave
      double acc = 0.0;
      if (o < 10) {
#pragma unroll
        for (int k = 0; k < 4; ++k)
          acc += xd[lane * 4 + k] * (double)cls_w[(lane * 4 + k) * 10 + o];
      } else {
        int oo = o - 10;
#pragma unroll
        for (int k = 0; k < 4; ++k)
          acc += xd[lane * 4 + k] * (double)reg_w[(lane * 4 + k) * 20 + oo];
      }
#pragma unroll
      for (int off = 32; off > 0; off >>= 1) acc += __shfl_down(acc, off);
      if (lane == 0) outv[o] = acc;
    }
  }
  __syncthreads();

  if (t < 5) {
    const int a = t;
    double l0 = outv[2 * a] + (double)cls_b[2 * a];
    double l1 = outv[2 * a + 1] + (double)cls_b[2 * a + 1];
    double sc = 1.0 / (1.0 + exp(l0 - l1));  // == softmax[...,1]
    const int n = p * 5 + a;
    scores[n] = sc;
    double d0 = outv[10 + 4 * a + 0] + (double)reg_b[4 * a + 0];
    double d1 = outv[10 + 4 * a + 1] + (double)reg_b[4 * a + 1];
    double d2 = outv[10 + 4 * a + 2] + (double)reg_b[4 * a + 2];
    double d3 = outv[10 + 4 * a + 3] + (double)reg_b[4 * a + 3];
    double scale = (double)(32 << a);  // 32,64,128,256,512 (ratio=1)
    double wdt = exp(d2) * scale;
    double hgt = exp(d3) * scale;
    double xc = (double)(p % W) + d0;  // FEATURE_STRIDE = 1
    double yc = (double)(p / W) + d1;
    boxes[n * 4 + 0] = xc - 0.5 * wdt;
    boxes[n * 4 + 1] = yc - 0.5 * hgt;
    boxes[n * 4 + 2] = xc + 0.5 * wdt;
    boxes[n * 4 + 3] = yc + 0.5 * hgt;
  }
}

// ---------------------------------------------------------------------------
// Kernel 3: exact stable descending rank, fully parallel: 32 slices of 250 j
// per box i, shfl-reduce over the 32-subgroup. Grid 1000 x 256.
// ---------------------------------------------------------------------------
__global__ __launch_bounds__(256) void rank_kernel(
    const double* __restrict__ scores, const double* __restrict__ boxes,
    double* __restrict__ bs, double* __restrict__ area) {
  const int gid = blockIdx.x * 256 + threadIdx.x;
  const int i = gid >> 5;
  const int js = gid & 31;
  if (i >= NBOX) return;
  const double si = scores[i];
  int cnt = 0;
  const int j0 = js * 250;
#pragma unroll 5
  for (int j = j0; j < j0 + 250; ++j) {
    double sj = scores[j];
    cnt += (sj > si || (sj == si && j < i)) ? 1 : 0;
  }
#pragma unroll
  for (int off = 16; off > 0; off >>= 1) cnt += __shfl_down(cnt, off, 32);
  if (js == 0) {
    double b0 = boxes[i * 4 + 0], b1 = boxes[i * 4 + 1];
    double b2 = boxes[i * 4 + 2], b3 = boxes[i * 4 + 3];
    bs[cnt * 4 + 0] = b0;
    bs[cnt * 4 + 1] = b1;
    bs[cnt * 4 + 2] = b2;
    bs[cnt * 4 + 3] = b3;
    area[cnt] = (b2 - b0) * (b3 - b1);
  }
}

// ---------------------------------------------------------------------------
// Kernel 4a: suppression bit-matrix. Grid = exactly the 7875 upper-tri
// tiles (u -> (ti,tj) unrank). Div-free: inter >= 0.7*union.
// ---------------------------------------------------------------------------
__global__ __launch_bounds__(256) void iou_matrix_kernel(
    const double* __restrict__ bs, const double* __restrict__ area,
    unsigned long long* __restrict__ supmat) {
  __shared__ double jx1[64], jy1[64], jx2[64], jy2[64], ja[64];
  __shared__ double ix1[64], iy1[64], ix2[64], iy2[64], ia[64];
  // unrank upper-tri index u -> (ti, tj), tj >= ti
  int u = blockIdx.x;
  int ti = 0, base = 0;
  while (u - base >= NCH - ti) {
    base += NCH - ti;
    ti++;
  }
  const int tj = ti + (u - base);
  const int t = threadIdx.x, wv = t >> 6, lane = t & 63;
  if (t < 64) {
    int j = tj * 64 + t;
    jx1[t] = bs[j * 4 + 0];
    jy1[t] = bs[j * 4 + 1];
    jx2[t] = bs[j * 4 + 2];
    jy2[t] = bs[j * 4 + 3];
    ja[t] = area[j];
  } else if (t < 128) {
    int l = t - 64;
    int i = ti * 64 + l;
    ix1[l] = bs[i * 4 + 0];
    iy1[l] = bs[i * 4 + 1];
    ix2[l] = bs[i * 4 + 2];
    iy2[l] = bs[i * 4 + 3];
    ia[l] = area[i];
  }
  __syncthreads();
  const double x1 = jx1[lane], y1 = jy1[lane], x2 = jx2[lane], y2 = jy2[lane];
  const double aj = ja[lane];
  const int jglob = tj * 64 + lane;
#pragma unroll 4
  for (int s = 0; s < 16; ++s) {
    const int il = wv * 16 + s;
    const int i = ti * 64 + il;
    const double bx1 = ix1[il], by1 = iy1[il], bx2 = ix2[il], by2 = iy2[il];
    const double ai = ia[il];
    double iw = fmin(x2, bx2) - fmax(x1, bx1);
    iw = iw > 0.0 ? iw : 0.0;
    double ih = fmin(y2, by2) - fmax(y1, by1);
    ih = ih > 0.0 ? ih : 0.0;
    double inter = iw * ih;
    bool sup = (jglob > i) && (inter >= 0.7 * (ai + aj - inter));
    unsigned long long wmask = __ballot(sup ? 1 : 0);
    if (lane == 0) supmat[(size_t)i * ROWW + tj] = wmask;
  }
}

// ---------------------------------------------------------------------------
// Kernel 4b: greedy resolution, 1024 threads, 1 barrier/chunk.
// Wave0: resolve chunk tc using mask[tc] | crit (crit computed last iter
// from the speculatively prefetched column). Waves 1-7: propagate chunk
// tc-1's kept rows into mask words >= tc+1 (parallel over rows x words).
// ---------------------------------------------------------------------------
__global__ __launch_bounds__(1024) void nms_serial_kernel(
    const double* __restrict__ bs,
    const unsigned long long* __restrict__ supmat,
    float* __restrict__ rois_out) {
  __shared__ unsigned long long mask[NCH];
  __shared__ int selK[MAXDET];
  __shared__ int kbl[2][64];
  __shared__ int kcnt_sh[2];
  __shared__ int nk_sh;
  const int t = threadIdx.x, lane = t & 63;

  for (int q = t; q < NCH; q += 1024) mask[q] = 0ull;
  if (t == 0) {
    kcnt_sh[0] = kcnt_sh[1] = 0;
    nk_sh = 0;
  }
  __syncthreads();

  unsigned long long wdiag = 0ull, wcrit = 0ull, crit = 0ull;
  if (t < 64) {
    wdiag = supmat[(size_t)lane * ROWW + 0];
    wcrit = supmat[(size_t)lane * ROWW + 1];  // NCH > 1
  }
  int nk = 0;
  for (int tc = 0; tc < NCH; ++tc) {
    const int par = tc & 1;
    if (t < 64) {
      unsigned long long m = mask[tc] | crit;
      unsigned long long cand = ~m;
      unsigned long long keptbits = 0ull;
      int cnt = 0;
      while (cand && nk < MAXDET) {  // uniform serial loop
        int b = __ffsll(cand) - 1;
        unsigned long long bit = 1ull << b;
        keptbits |= bit;
        if (lane == 0) {
          selK[nk] = tc * 64 + b;
          kbl[par][cnt] = b;
        }
        cnt++;
        nk++;
        unsigned long long row = __shfl(wdiag, b);
        cand &= ~(row | bit);
      }
      // crit for chunk tc+1: OR of prefetched column tc+1 over kept lanes.
      unsigned long long v = ((keptbits >> lane) & 1ull) ? wcrit : 0ull;
#pragma unroll
      for (int off = 32; off > 0; off >>= 1) v |= __shfl_xor(v, off);
      crit = v;
      // prefetch chunk tc+1's diag and crit columns (guard past NCH).
      if (tc + 1 < NCH) {
        wdiag = supmat[(size_t)((tc + 1) * 64 + lane) * ROWW + (tc + 1)];
        wcrit = (tc + 2 < NCH)
                    ? supmat[(size_t)((tc + 1) * 64 + lane) * ROWW + (tc + 2)]
                    : 0ull;
      }
      if (lane == 0) {
        kcnt_sh[par] = cnt;
        nk_sh = nk;
      }
    } else if (tc > 0) {
      // propagate chunk tc-1's kept rows into words >= tc+1.
      const int pp = par ^ 1;
      const int k = kcnt_sh[pp];
      const int ptc = tc - 1;
      const int w0 = ptc + 2;  // == tc+1
      const int nwords = NCH - w0;
      if (k > 0 && nwords > 0) {
        const int npairs = k * nwords;
        for (int q = t - 64; q < npairs; q += 1024 - 64) {
          int b = kbl[pp][q / nwords];
          int w = w0 + q % nwords;
          unsigned long long r = supmat[(size_t)(ptc * 64 + b) * ROWW + w];
          if (r) {
            unsigned int* mw = (unsigned int*)&mask[w];
            unsigned int lo = (unsigned int)r;
            unsigned int hi = (unsigned int)(r >> 32);
            if (lo) atomicOr(&mw[0], lo);
            if (hi) atomicOr(&mw[1], hi);
          }
        }
      }
    }
    __syncthreads();
    nk = nk_sh;
    if (nk >= MAXDET) break;
  }
  __syncthreads();

  const int NK = nk < MAXDET ? nk : MAXDET;
  for (int r = t; r < MAXDET; r += 1024) {
    if (r < NK) {
      int p = selK[r];
      rois_out[r * 4 + 0] = (float)bs[p * 4 + 0];
      rois_out[r * 4 + 1] = (float)bs[p * 4 + 1];
      rois_out[r * 4 + 2] = (float)bs[p * 4 + 2];
      rois_out[r * 4 + 3] = (float)bs[p * 4 + 3];
    } else {  // rois = b[sel] * 0 exactly
      rois_out[r * 4 + 0] = 0.f;
      rois_out[r * 4 + 1] = 0.f;
      rois_out[r * 4 + 2] = 0.f;
      rois_out[r * 4 + 3] = 0.f;
    }
  }
}

// ---------------------------------------------------------------------------
// Kernel 5: FC head (fp32; tolerances generous, softmax saturated).
// ---------------------------------------------------------------------------
__global__ __launch_bounds__(256) void rcnn_head_kernel(
    const float* __restrict__ rois, const float* __restrict__ fc1_w,
    const float* __restrict__ fc1_b, const float* __restrict__ clsh_w,
    const float* __restrict__ clsh_b, const float* __restrict__ regh_w,
    const float* __restrict__ regh_b, float* __restrict__ out) {
  __shared__ float red[256 * 8];
  const int r = blockIdx.x, t = threadIdx.x;
  const float r0 = rois[r * 4 + 0], r1 = rois[r * 4 + 1];
  const float r2 = rois[r * 4 + 2], r3 = rois[r * 4 + 3];
  float pc[4] = {0, 0, 0, 0}, pb[4] = {0, 0, 0, 0};
#pragma unroll
  for (int q = 0; q < 4; ++q) {
    int j = t * 4 + q;
    float f = r0 * fc1_w[j] + r1 * fc1_w[1024 + j] + r2 * fc1_w[2048 + j] +
              r3 * fc1_w[3072 + j] + fc1_b[j];
    f = fmaxf(f, 0.f);
#pragma unroll
    for (int c = 0; c < 4; ++c) {
      pc[c] += f * clsh_w[j * 4 + c];
      pb[c] += f * regh_w[j * 4 + c];
    }
  }
#pragma unroll
  for (int u = 0; u < 4; ++u) {
    red[t * 8 + u] = pc[u];
    red[t * 8 + 4 + u] = pb[u];
  }
  __syncthreads();
  for (int s = 128; s > 0; s >>= 1) {
    if (t < s) {
#pragma unroll
      for (int u = 0; u < 8; ++u) red[t * 8 + u] += red[(t + s) * 8 + u];
    }
    __syncthreads();
  }
  if (t == 0) {
    float lg[4];
    float m = -1e30f;
#pragma unroll
    for (int c = 0; c < 4; ++c) {
      lg[c] = red[c] + clsh_b[c];
      m = fmaxf(m, lg[c]);
    }
    float s = 0.f;
#pragma unroll
    for (int c = 0; c < 4; ++c) {
      lg[c] = expf(lg[c] - m);
      s += lg[c];
    }
#pragma unroll
    for (int c = 0; c < 4; ++c) out[r * 4 + c] = lg[c] / s;
#pragma unroll
    for (int k = 0; k < 4; ++k)
      out[1200 + r * 4 + k] = red[4 + k] + regh_b[k];
  }
}

// ---------------------------------------------------------------------------
extern "C" void kernel_launch(void* const* d_in, const int* in_sizes, int n_in,
                              void* d_out, int out_size, void* d_ws,
                              size_t ws_size, hipStream_t stream) {
  const float* feat = (const float*)d_in[0];
  const float* conv_w = (const float*)d_in[1];
  const float* conv_b = (const float*)d_in[2];
  const float* cls_w = (const float*)d_in[3];
  const float* cls_b = (const float*)d_in[4];
  const float* reg_w = (const float*)d_in[5];
  const float* reg_b = (const float*)d_in[6];
  const float* fc1_w = (const float*)d_in[7];
  const float* fc1_b = (const float*)d_in[8];
  const float* clsh_w = (const float*)d_in[9];
  const float* clsh_b = (const float*)d_in[10];
  const float* regh_w = (const float*)d_in[11];
  const float* regh_b = (const float*)d_in[12];
  float* out = (float*)d_out;

  char* w = (char*)d_ws;
  double* xsum = (double*)(w);                 // 1600*256*8   = 3,276,800 B
  double* scores = (double*)(w + 3276800);     // 8000*8       =    64,000 B
  double* boxes = (double*)(w + 3340800);      // 8000*4*8     =   256,000 B
  double* bs = (double*)(w + 3596800);         // 8000*4*8     =   256,000 B
  double* area = (double*)(w + 3852800);       // 8000*8       =    64,000 B
  unsigned long long* supmat =
      (unsigned long long*)(w + 3916800);      // 8000*128*8   = 8,192,000 B
  double* part = (double*)(w + 12108800);      // 32*3,276,800 = 104,857,600 B
  // deterministic per-problem: same branch every call (graph-safe)
  const int use_part = (ws_size >= (size_t)12108800 + 104857600ull) ? 1 : 0;

  if (!use_part) hipMemsetAsync(xsum, 0, 3276800, stream);
  conv3x3_kernel<<<1280, 512, 0, stream>>>(feat, conv_w, xsum, part, use_part);
  heads_kernel<<<1600, 256, 0, stream>>>(xsum, part, use_part, conv_b, cls_w,
                                         cls_b, reg_w, reg_b, scores, boxes);
  rank_kernel<<<1000, 256, 0, stream>>>(scores, boxes, bs, area);
  iou_matrix_kernel<<<NTRI, 256, 0, stream>>>(bs, area, supmat);
  nms_serial_kernel<<<1, 1024, 0, stream>>>(bs, supmat, out + 2400);
  rcnn_head_kernel<<<300, 256, 0, stream>>>(out + 2400, fc1_w, fc1_b, clsh_w,
                                            clsh_b, regh_w, regh_b, out);
}